// Round 1
// 155.924 us; speedup vs baseline: 1.0047x; 1.0047x over previous
//
#include <hip/hip_runtime.h>
#include <hip/hip_bf16.h>

// Mex forward: B=64,C=64,H=W=64, BLK=(64,3,3), STR=(64,2,2), PAD=(0,1,1),
// NI=256, EPS=1, mean mode. OH=OW=32, K=576, out (64,256,32,32) fp32.
//
// y[n][i] = log( sum_k exp(P[n][k] + O[i][k]) ) - log(576)
// Shift-invariant -> no max pass. Zero-padded entries -> exp(0)=1.
//
// FUSED pipeline (v2): the old mex_exp_tr kernel (exp(x)->bf16 transpose to a
// 33.5 MB intermediate E, re-read by main) accounted for ~95 us of wall time
// while mex_main sat latency-bound at 12% MfmaUtil / 19% HBM. Now each main
// block register-stages its own 5 rows of x (fp32, coalesced float2 loads),
// does exp->bf16 in-register, and ds_write_b128's into the SAME swizzled LDS
// layout the async DMA used to produce. E is gone.
//
//   1) mex_prep_b : Bt[i][k'] = bf16(exp(off)), k' = (fh*3+fw)*64 + c
//   2) mex_main   : per (b, oh-pair): reg-stage 5 rows of exp(x) into LDS
//                   (swizzled chunk pos = c8 ^ ((w>>1)&7)), barrier,
//                   18-step barrier-free MFMA K-loop, log-epilogue.

typedef __bf16 bf16x8 __attribute__((ext_vector_type(8)));
typedef float  f32x4  __attribute__((ext_vector_type(4)));

// ---- Bt[i][k'] = bf16(exp(offsets[i][c][fh][fw])), k' = p*64 + c ----------
__global__ void mex_prep_b(const float* __restrict__ off, __bf16* __restrict__ Bt) {
    const int i = blockIdx.x * 4 + (threadIdx.x >> 6);  // instance
    const int c = threadIdx.x & 63;
    const float* oi = off + i * 576;
    __bf16* bi = Bt + i * 576;
    #pragma unroll
    for (int p = 0; p < 9; ++p) {
        float v = oi[c * 9 + p];     // original k = c*9 + p
        bi[p * 64 + c] = (__bf16)__expf(v);
    }
}

// ---- main fused kernel ----------------------------------------------------
__global__ __launch_bounds__(256, 3) void mex_main(
        const float* __restrict__ x,
        const __bf16* __restrict__ Bt,
        float* __restrict__ out) {
    // [hl 0..4][w_idx 0..65][chunk 0..7] bf16x8; w_idx = w_global+1. 42240 B.
    __shared__ bf16x8 lds8[5 * 66 * 8];

    const int bid = blockIdx.x;      // 0..1023
    const int b   = bid >> 4;
    const int oh0 = (bid & 15) << 1;
    const int tid  = threadIdx.x;
    const int wv   = tid >> 6;

    // ---- pad fills (LDS stores) ------------------------------------------
    bf16x8 one8;
    #pragma unroll
    for (int j = 0; j < 8; ++j) one8[j] = (__bf16)1.0f;
    if (tid < 40) {                  // w_idx = 0 column (w_global = -1)
        const int hl = tid >> 3, cc = tid & 7;
        lds8[(hl * 66) * 8 + cc] = one8;
    }
    if (oh0 == 0) {                  // h_global = -1 -> whole hl=0 row = ones
        for (int i = tid; i < 66 * 8; i += 256) lds8[i] = one8;
    }

    // ---- fused staging: x -> exp -> bf16 -> swizzled LDS -----------------
    // thread t: w-pair wp = t&31 (w0 = 2*wp), c-chunk c8 = t>>5.
    // Per row: 8 coalesced float2 loads (two 256B segments per wave-half),
    // 16 expf, 2 ds_write_b128 at swizzled chunk slot c8 ^ (wp&7)
    // (== c8 ^ ((w>>1)&7) for both w0 and w0+1 since w0 is even), which is
    // exactly what the reader's key = ((w_idx-1)>>1)&7 expects.
    {
        const int wp  = tid & 31;
        const int w0  = wp << 1;
        const int c8  = tid >> 5;
        const int c8p = c8 ^ (wp & 7);
        const float* xb = x + ((size_t)b << 18) + w0;   // + c*4096 + h*64
        #pragma unroll
        for (int hl = 0; hl < 5; ++hl) {
            const int hg = 2 * oh0 - 1 + hl;            // -1..63
            if (hg >= 0) {                              // wave-uniform
                const float* xp = xb + (hg << 6);
                float2 v[8];
                #pragma unroll
                for (int k = 0; k < 8; ++k)
                    v[k] = *(const float2*)(xp + (((c8 << 3) + k) << 12));
                bf16x8 ca, cb;
                #pragma unroll
                for (int k = 0; k < 8; ++k) {
                    ca[k] = (__bf16)__expf(v[k].x);
                    cb[k] = (__bf16)__expf(v[k].y);
                }
                bf16x8* dst = lds8 + hl * 528 + (w0 + 1) * 8 + c8p;
                dst[0] = ca;        // w_idx = w0+1
                dst[8] = cb;        // w_idx = w0+2 (same swizzle slot)
            }
        }
    }
    __syncthreads();   // staging + pad writes visible; only barrier

    const int t16 = tid & 15;
    const int q   = (tid >> 4) & 3;

    int rbase[4], owv[4];
    #pragma unroll
    for (int mt = 0; mt < 4; ++mt) {
        const int m = mt * 16 + t16;
        owv[mt]   = m & 31;
        rbase[mt] = ((m >> 5) * 132) + ((m & 31) * 2);  // hl*66 + 2*ow part
    }

    const bf16x8* __restrict__ Btv = (const bf16x8*)Bt;  // 72 chunks / inst
    const int instRow = (wv * 64 + t16) * 72 + q;

    f32x4 acc[4][4];
    #pragma unroll
    for (int mt = 0; mt < 4; ++mt)
        #pragma unroll
        for (int nt = 0; nt < 4; ++nt)
            acc[mt][nt] = (f32x4)(0.0f);

    bf16x8 bcur[4];
    #pragma unroll
    for (int nt = 0; nt < 4; ++nt)
        bcur[nt] = Btv[instRow + nt * (16 * 72)];

    #pragma unroll 2
    for (int ks = 0; ks < 18; ++ks) {
        const int p  = ks >> 1;
        const int fh = (p * 11) >> 5;              // p/3
        const int fw = p - fh * 3;
        const int rofs = fh * 66 + fw;
        const int ccq  = ((ks & 1) << 2) + q;

        bf16x8 a[4];
        #pragma unroll
        for (int mt = 0; mt < 4; ++mt) {
            const int row = rbase[mt] + rofs;      // hl*66 + w_idx
            const int key = ((owv[mt] * 2 + fw - 1) >> 1) & 7;  // w-only swizzle
            a[mt] = lds8[row * 8 + (ccq ^ key)];
        }

        bf16x8 bnext[4];
        if (ks < 17) {
            #pragma unroll
            for (int nt = 0; nt < 4; ++nt)
                bnext[nt] = Btv[instRow + nt * (16 * 72) + (ks + 1) * 4];
        }

        #pragma unroll
        for (int mt = 0; mt < 4; ++mt)
            #pragma unroll
            for (int nt = 0; nt < 4; ++nt)
                acc[mt][nt] = __builtin_amdgcn_mfma_f32_16x16x32_bf16(
                    a[mt], bcur[nt], acc[mt][nt], 0, 0, 0);

        #pragma unroll
        for (int nt = 0; nt < 4; ++nt) bcur[nt] = bnext[nt];
    }

    // ---- epilogue: y = log(S) - log(576) ---------------------------------
    const float lK = 6.356107660695891f;   // log(576)
    #pragma unroll
    for (int mt = 0; mt < 4; ++mt) {
        const int m   = mt * 16 + (q << 2);        // C/D: row = q*4 + reg
        const int ohl = m >> 5;
        const int owi = m & 31;
        const int orow = (oh0 + ohl) * 32 + owi;
        #pragma unroll
        for (int nt = 0; nt < 4; ++nt) {
            const int inst = wv * 64 + nt * 16 + t16;   // C/D: col = lane&15
            f32x4 r;
            #pragma unroll
            for (int j = 0; j < 4; ++j)
                r[j] = __logf(acc[mt][nt][j]) - lK;
            *(f32x4*)(out + (((size_t)b * 256 + inst) * 1024 + orow)) = r;
        }
    }
}

extern "C" void kernel_launch(void* const* d_in, const int* in_sizes, int n_in,
                              void* d_out, int out_size, void* d_ws, size_t ws_size,
                              hipStream_t stream) {
    const float* x   = (const float*)d_in[0];   // (64,64,64,64) fp32
    const float* off = (const float*)d_in[1];   // (1,256,64,3,3) fp32
    float* out = (float*)d_out;                 // (64,256,32,32) fp32
    __bf16* Bt = (__bf16*)d_ws;                 // 294912 B

    mex_prep_b<<<64, 256, 0, stream>>>(off, Bt);
    mex_main<<<1024, 256, 0, stream>>>(x, Bt, out);
}

// Round 3
// 152.052 us; speedup vs baseline: 1.0303x; 1.0255x over previous
//
#include <hip/hip_runtime.h>
#include <hip/hip_bf16.h>

// Mex forward: B=64,C=64,H=W=64, BLK=(64,3,3), STR=(64,2,2), PAD=(0,1,1),
// NI=256, EPS=1, mean mode. OH=OW=32, K=576, out (64,256,32,32) fp32.
//
// y[n][i] = log( sum_k exp(P[n][k] + O[i][k]) ) - log(576)
// Shift-invariant -> no max pass. Zero-padded entries -> exp(0)=1.
//
// v3b: v3 with the hb[] indexing bug fixed (hl = 2*ohl + fh, so the ohl part
//      contributes ohl*128 LDS rows-of-8, not ohl*64).
// v3: - LDS cut to exactly 40960 B (5 x 64 x 8 bf16x8 chunks, no stored pad
//       columns) -> 4 blocks/CU, grid 1024 fully co-resident, no tail.
//       Left pad (w=-1, only fw==0 & ow==0) handled with in-register ones
//       select; right/bottom edges are never padded for this conv geometry.
//     - Bt re-laid out as BtL[(ks*16 + wv*4 + nt)*64 + (q*16+t16)] so every
//       B fetch in the K-loop is one fully-coalesced 1 KB wave load from L2
//       (was: 64 lanes x 16 B scattered over 18 KB, 72 gathers per wave).
//     - K-loop fully unrolled (fh/fw/pad checks constant-folded).
//     - first B fragments issued before the barrier.

typedef __bf16 bf16x8 __attribute__((ext_vector_type(8)));
typedef float  f32x4  __attribute__((ext_vector_type(4)));

// ---- BtL[(ks*16 + wv*4 + nt)*64 + q*16 + t16][j] = bf16(exp(off[i][c][p]))
// where inst i = wv*64+nt*16+t16, c = c8*8+j, ks = 2*p + (c8>>2), q = c8&3.
__global__ void mex_prep_b(const float* __restrict__ off, __bf16* __restrict__ Bt) {
    const int i = blockIdx.x * 4 + (threadIdx.x >> 6);  // instance
    const int c = threadIdx.x & 63;                     // channel
    const int c8 = c >> 3, j = c & 7;
    const int wv = i >> 6, nt = (i >> 4) & 3, t16 = i & 15;
    const int q  = c8 & 3;
    const float* oi = off + i * 576;
    #pragma unroll
    for (int p = 0; p < 9; ++p) {
        float v = oi[c * 9 + p];                        // original k = c*9 + p
        const int ks    = p * 2 + (c8 >> 2);
        const int chunk = (ks * 16 + wv * 4 + nt) * 64 + q * 16 + t16;
        Bt[chunk * 8 + j] = (__bf16)__expf(v);
    }
}

// ---- main fused kernel ----------------------------------------------------
__global__ __launch_bounds__(256, 4) void mex_main(
        const float* __restrict__ x,
        const __bf16* __restrict__ Bt,
        float* __restrict__ out) {
    // [hl 0..4][w 0..63][chunk 0..7] bf16x8; w = global w. 40960 B exactly.
    __shared__ bf16x8 lds8[5 * 64 * 8];

    const int bid = blockIdx.x;      // 0..1023
    const int b   = bid >> 4;
    const int oh0 = (bid & 15) << 1;
    const int tid  = threadIdx.x;
    const int wv   = tid >> 6;
    const int lane = tid & 63;

    bf16x8 one8;
    #pragma unroll
    for (int j = 0; j < 8; ++j) one8[j] = (__bf16)1.0f;

    // ---- top pad: h_global = -1 -> whole hl=0 row = ones -----------------
    if (oh0 == 0) {
        #pragma unroll
        for (int i = 0; i < 2; ++i) lds8[tid + i * 256] = one8;
    }

    // ---- fused staging: x -> exp -> bf16 -> swizzled LDS -----------------
    // thread t: w-pair wp = t&31 (w0 = 2*wp), c-chunk c8 = t>>5.
    // Swizzled chunk slot c8 ^ (wp&7) == c8 ^ ((w>>1)&7) for both w0, w0+1.
    {
        const int wp  = tid & 31;
        const int w0  = wp << 1;
        const int c8  = tid >> 5;
        const int c8p = c8 ^ (wp & 7);
        const float* xb = x + ((size_t)b << 18) + w0;   // + c*4096 + h*64
        #pragma unroll
        for (int hl = 0; hl < 5; ++hl) {
            const int hg = 2 * oh0 - 1 + hl;            // -1..63
            if (hg >= 0) {                              // block-uniform
                const float* xp = xb + (hg << 6);
                float2 v[8];
                #pragma unroll
                for (int k = 0; k < 8; ++k)
                    v[k] = *(const float2*)(xp + (((c8 << 3) + k) << 12));
                bf16x8 ca, cb;
                #pragma unroll
                for (int k = 0; k < 8; ++k) {
                    ca[k] = (__bf16)__expf(v[k].x);
                    cb[k] = (__bf16)__expf(v[k].y);
                }
                bf16x8* dst = lds8 + hl * 512 + w0 * 8 + c8p;
                dst[0] = ca;        // w = w0
                dst[8] = cb;        // w = w0+1 (same swizzle slot)
            }
        }
    }

    // ---- first B fragments: in flight across the barrier -----------------
    const bf16x8* __restrict__ Btv = (const bf16x8*)Bt;
    const int wv4 = wv << 2;
    bf16x8 bcur[4];
    #pragma unroll
    for (int nt = 0; nt < 4; ++nt)
        bcur[nt] = Btv[(wv4 + nt) * 64 + lane];         // ks = 0

    __syncthreads();   // staging + pad writes visible; only barrier

    const int t16 = tid & 15;
    const int q   = (tid >> 4) & 3;

    int hb[4], wo2[4];
    #pragma unroll
    for (int mt = 0; mt < 4; ++mt) {
        const int m = mt * 16 + t16;
        wo2[mt] = (m & 31) << 1;      // 2*ow
        hb[mt]  = (m >> 5) << 7;      // (2*ohl) * 64  [v3 bug: was <<6]
    }

    f32x4 acc[4][4];
    #pragma unroll
    for (int mt = 0; mt < 4; ++mt)
        #pragma unroll
        for (int nt = 0; nt < 4; ++nt)
            acc[mt][nt] = (f32x4)(0.0f);

    #pragma unroll
    for (int ks = 0; ks < 18; ++ks) {
        const int p  = ks >> 1;
        const int fh = (p * 11) >> 5;              // p/3 (const after unroll)
        const int fw = p - fh * 3;
        const int ccq = ((ks & 1) << 2) + q;

        bf16x8 a[4];
        #pragma unroll
        for (int mt = 0; mt < 4; ++mt) {
            const int wc  = wo2[mt] + fw - 1;      // w_global, -1..63
            const int pad = wc < 0;                // only fw==0 & ow==0
            const int wcl = pad ? 0 : wc;
            const int row = hb[mt] + fh * 64 + wcl;   // (2*ohl+fh)*64 + w
            bf16x8 vv = lds8[row * 8 + (ccq ^ ((wcl >> 1) & 7))];
            a[mt] = pad ? one8 : vv;
        }

        bf16x8 bnext[4];
        if (ks < 17) {
            #pragma unroll
            for (int nt = 0; nt < 4; ++nt)
                bnext[nt] = Btv[((ks + 1) * 16 + wv4 + nt) * 64 + lane];
        }

        #pragma unroll
        for (int mt = 0; mt < 4; ++mt)
            #pragma unroll
            for (int nt = 0; nt < 4; ++nt)
                acc[mt][nt] = __builtin_amdgcn_mfma_f32_16x16x32_bf16(
                    a[mt], bcur[nt], acc[mt][nt], 0, 0, 0);

        #pragma unroll
        for (int nt = 0; nt < 4; ++nt) bcur[nt] = bnext[nt];
    }

    // ---- epilogue: y = log(S) - log(576) ---------------------------------
    const float lK = 6.356107660695891f;   // log(576)
    #pragma unroll
    for (int mt = 0; mt < 4; ++mt) {
        const int m   = mt * 16 + (q << 2);        // C/D: row = q*4 + reg
        const int ohl = m >> 5;
        const int owi = m & 31;
        const int orow = (oh0 + ohl) * 32 + owi;
        #pragma unroll
        for (int nt = 0; nt < 4; ++nt) {
            const int inst = wv * 64 + nt * 16 + t16;   // C/D: col = lane&15
            f32x4 r;
            #pragma unroll
            for (int j = 0; j < 4; ++j)
                r[j] = __logf(acc[mt][nt][j]) - lK;
            *(f32x4*)(out + (((size_t)b * 256 + inst) * 1024 + orow)) = r;
        }
    }
}

extern "C" void kernel_launch(void* const* d_in, const int* in_sizes, int n_in,
                              void* d_out, int out_size, void* d_ws, size_t ws_size,
                              hipStream_t stream) {
    const float* x   = (const float*)d_in[0];   // (64,64,64,64) fp32
    const float* off = (const float*)d_in[1];   // (1,256,64,3,3) fp32
    float* out = (float*)d_out;                 // (64,256,32,32) fp32
    __bf16* Bt = (__bf16*)d_ws;                 // 294912 B

    mex_prep_b<<<64, 256, 0, stream>>>(off, Bt);
    mex_main<<<1024, 256, 0, stream>>>(x, Bt, out);
}

// Round 4
// 148.882 us; speedup vs baseline: 1.0522x; 1.0213x over previous
//
#include <hip/hip_runtime.h>
#include <hip/hip_bf16.h>

// Mex forward: B=64,C=64,H=W=64, BLK=(64,3,3), STR=(64,2,2), PAD=(0,1,1),
// NI=256, EPS=1, mean mode. OH=OW=32, K=576, out (64,256,32,32) fp32.
//
// y[n][i] = log( sum_k exp(P[n][k] + O[i][k]) ) - log(576)
// Shift-invariant -> no max pass. Zero-padded entries -> exp(0)=1.
//
// v4: - Epilogue restructured: accumulators are staged through LDS (reusing
//       the 40 KB A-tile buffer, two 36,864 B passes, one per output row) so
//       every 128 B out cache line is written WHOLE by a single store
//       instruction (8 lanes x 16 B). v3b wrote each line as 2 x 64 B from
//       two stores -> WRITE_SIZE showed 128 MB for a 67 MB output.
//     - XCD-chunked blockIdx swizzle: the 16 blocks sharing a batch image b
//       (overlapping halo rows + same Bt) land on one XCD's L2.
// v3: LDS = 40960 B exactly (4 blocks/CU, grid fully resident); left pad via
//     in-register ones-select; Bt laid out for 1 KB coalesced wave loads;
//     K-loop fully unrolled; first B fragments prefetched across the barrier.

typedef __bf16 bf16x8 __attribute__((ext_vector_type(8)));
typedef float  f32x4  __attribute__((ext_vector_type(4)));

// ---- BtL[(ks*16 + wv*4 + nt)*64 + q*16 + t16][j] = bf16(exp(off[i][c][p]))
// where inst i = wv*64+nt*16+t16, c = c8*8+j, ks = 2*p + (c8>>2), q = c8&3.
__global__ void mex_prep_b(const float* __restrict__ off, __bf16* __restrict__ Bt) {
    const int i = blockIdx.x * 4 + (threadIdx.x >> 6);  // instance
    const int c = threadIdx.x & 63;                     // channel
    const int c8 = c >> 3, j = c & 7;
    const int wv = i >> 6, nt = (i >> 4) & 3, t16 = i & 15;
    const int q  = c8 & 3;
    const float* oi = off + i * 576;
    #pragma unroll
    for (int p = 0; p < 9; ++p) {
        float v = oi[c * 9 + p];                        // original k = c*9 + p
        const int ks    = p * 2 + (c8 >> 2);
        const int chunk = (ks * 16 + wv * 4 + nt) * 64 + q * 16 + t16;
        Bt[chunk * 8 + j] = (__bf16)__expf(v);
    }
}

// ---- main fused kernel ----------------------------------------------------
__global__ __launch_bounds__(256, 4) void mex_main(
        const float* __restrict__ x,
        const __bf16* __restrict__ Bt,
        float* __restrict__ out) {
    // [hl 0..4][w 0..63][chunk 0..7] bf16x8; w = global w. 40960 B exactly.
    // Reused after the K-loop as a 256x36 f32 transpose buffer (36,864 B).
    __shared__ bf16x8 lds8[5 * 64 * 8];

    const int bid = blockIdx.x;      // 0..1023
    // XCD-chunked swizzle (8 XCDs, 1024 % 8 == 0 -> bijective): XCD k gets
    // work ids k*128..k*128+127 = batches b = 8k..8k+7, all oh0.
    const int w   = ((bid & 7) << 7) | (bid >> 3);
    const int b   = w >> 4;
    const int oh0 = (w & 15) << 1;
    const int tid  = threadIdx.x;
    const int wv   = tid >> 6;
    const int lane = tid & 63;

    bf16x8 one8;
    #pragma unroll
    for (int j = 0; j < 8; ++j) one8[j] = (__bf16)1.0f;

    // ---- top pad: h_global = -1 -> whole hl=0 row = ones -----------------
    if (oh0 == 0) {
        #pragma unroll
        for (int i = 0; i < 2; ++i) lds8[tid + i * 256] = one8;
    }

    // ---- fused staging: x -> exp -> bf16 -> swizzled LDS -----------------
    // thread t: w-pair wp = t&31 (w0 = 2*wp), c-chunk c8 = t>>5.
    // Swizzled chunk slot c8 ^ (wp&7) == c8 ^ ((w>>1)&7) for both w0, w0+1.
    {
        const int wp  = tid & 31;
        const int w0  = wp << 1;
        const int c8  = tid >> 5;
        const int c8p = c8 ^ (wp & 7);
        const float* xb = x + ((size_t)b << 18) + w0;   // + c*4096 + h*64
        #pragma unroll
        for (int hl = 0; hl < 5; ++hl) {
            const int hg = 2 * oh0 - 1 + hl;            // -1..63
            if (hg >= 0) {                              // block-uniform
                const float* xp = xb + (hg << 6);
                float2 v[8];
                #pragma unroll
                for (int k = 0; k < 8; ++k)
                    v[k] = *(const float2*)(xp + (((c8 << 3) + k) << 12));
                bf16x8 ca, cb;
                #pragma unroll
                for (int k = 0; k < 8; ++k) {
                    ca[k] = (__bf16)__expf(v[k].x);
                    cb[k] = (__bf16)__expf(v[k].y);
                }
                bf16x8* dst = lds8 + hl * 512 + w0 * 8 + c8p;
                dst[0] = ca;        // w = w0
                dst[8] = cb;        // w = w0+1 (same swizzle slot)
            }
        }
    }

    // ---- first B fragments: in flight across the barrier -----------------
    const bf16x8* __restrict__ Btv = (const bf16x8*)Bt;
    const int wv4 = wv << 2;
    bf16x8 bcur[4];
    #pragma unroll
    for (int nt = 0; nt < 4; ++nt)
        bcur[nt] = Btv[(wv4 + nt) * 64 + lane];         // ks = 0

    __syncthreads();   // staging + pad writes visible

    const int t16 = tid & 15;
    const int q   = (tid >> 4) & 3;

    int hb[4], wo2[4];
    #pragma unroll
    for (int mt = 0; mt < 4; ++mt) {
        const int m = mt * 16 + t16;
        wo2[mt] = (m & 31) << 1;      // 2*ow
        hb[mt]  = (m >> 5) << 7;      // (2*ohl) * 64
    }

    f32x4 acc[4][4];
    #pragma unroll
    for (int mt = 0; mt < 4; ++mt)
        #pragma unroll
        for (int nt = 0; nt < 4; ++nt)
            acc[mt][nt] = (f32x4)(0.0f);

    #pragma unroll
    for (int ks = 0; ks < 18; ++ks) {
        const int p  = ks >> 1;
        const int fh = (p * 11) >> 5;              // p/3 (const after unroll)
        const int fw = p - fh * 3;
        const int ccq = ((ks & 1) << 2) + q;

        bf16x8 a[4];
        #pragma unroll
        for (int mt = 0; mt < 4; ++mt) {
            const int wc  = wo2[mt] + fw - 1;      // w_global, -1..63
            const int pad = wc < 0;                // only fw==0 & ow==0
            const int wcl = pad ? 0 : wc;
            const int row = hb[mt] + fh * 64 + wcl;   // (2*ohl+fh)*64 + w
            bf16x8 vv = lds8[row * 8 + (ccq ^ ((wcl >> 1) & 7))];
            a[mt] = pad ? one8 : vv;
        }

        bf16x8 bnext[4];
        if (ks < 17) {
            #pragma unroll
            for (int nt = 0; nt < 4; ++nt)
                bnext[nt] = Btv[((ks + 1) * 16 + wv4 + nt) * 64 + lane];
        }

        #pragma unroll
        for (int mt = 0; mt < 4; ++mt)
            #pragma unroll
            for (int nt = 0; nt < 4; ++nt)
                acc[mt][nt] = __builtin_amdgcn_mfma_f32_16x16x32_bf16(
                    a[mt], bcur[nt], acc[mt][nt], 0, 0, 0);

        #pragma unroll
        for (int nt = 0; nt < 4; ++nt) bcur[nt] = bnext[nt];
    }

    // ---- epilogue: y = log(S) - log(576), via LDS transpose --------------
    // Two passes (one per output row). LDS layout: [inst 0..255][36 f32]
    // (32 payload + 4 pad, 16B-aligned rows). Read-back streams full 128B
    // lines: 8 lanes x f32x4 per (inst, orow) row.
    const float lK = 6.356107660695891f;   // log(576)
    float* lds_f = (float*)lds8;
    __syncthreads();   // all waves done reading the A-tile
    #pragma unroll
    for (int ohl = 0; ohl < 2; ++ohl) {
        #pragma unroll
        for (int mt2 = 0; mt2 < 2; ++mt2) {
            const int mt  = ohl * 2 + mt2;
            const int owi = mt2 * 16 + (q << 2);   // C/D: row = q*4 + reg
            #pragma unroll
            for (int nt = 0; nt < 4; ++nt) {
                const int inst = wv * 64 + nt * 16 + t16;  // C/D: col = t16
                f32x4 r;
                #pragma unroll
                for (int j = 0; j < 4; ++j)
                    r[j] = __logf(acc[mt][nt][j]) - lK;
                *(f32x4*)(lds_f + inst * 36 + owi) = r;
            }
        }
        __syncthreads();
        float* ob = out + ((size_t)b << 18) + ((oh0 + ohl) << 5);
        #pragma unroll
        for (int s = 0; s < 8; ++s) {
            const int g    = tid + s * 256;        // 0..2047
            const int inst = g >> 3;
            const int owi  = (g & 7) << 2;
            f32x4 v = *(const f32x4*)(lds_f + inst * 36 + owi);
            *(f32x4*)(ob + inst * 1024 + owi) = v;
        }
        if (ohl == 0) __syncthreads();
    }
}

extern "C" void kernel_launch(void* const* d_in, const int* in_sizes, int n_in,
                              void* d_out, int out_size, void* d_ws, size_t ws_size,
                              hipStream_t stream) {
    const float* x   = (const float*)d_in[0];   // (64,64,64,64) fp32
    const float* off = (const float*)d_in[1];   // (1,256,64,3,3) fp32
    float* out = (float*)d_out;                 // (64,256,32,32) fp32
    __bf16* Bt = (__bf16*)d_ws;                 // 294912 B

    mex_prep_b<<<64, 256, 0, stream>>>(off, Bt);
    mex_main<<<1024, 256, 0, stream>>>(x, Bt, out);
}

// Round 5
// 143.815 us; speedup vs baseline: 1.0893x; 1.0352x over previous
//
#include <hip/hip_runtime.h>
#include <hip/hip_bf16.h>

// Mex forward: B=64,C=64,H=W=64, BLK=(64,3,3), STR=(64,2,2), PAD=(0,1,1),
// NI=256, EPS=1, mean mode. OH=OW=32, K=576, out (64,256,32,32) fp32.
//
// y[n][i] = log( sum_k exp(P[n][k] + O[i][k]) ) - log(576)
// Shift-invariant -> no max pass. Zero-padded entries -> exp(0)=1.
//
// v5: 2-tile software pipeline. Grid 512 x 256thr; each block does two
//     adjacent oh-pair tiles (same b). LDS = 2 x 40 KB buffers (80 KB,
//     2 blocks/CU = 160 KB exactly). While tile0's K-loop+epilogue run,
//     tile1's 40 global loads are in flight; tile0's epilogue (logf +
//     stores) is placed after the second barrier so it interleaves with
//     tile1's K-loop (VALU+VMEM vs MFMA+LDS). Breaks the global phase
//     lockstep of v3/v4 (all blocks staging, then all MFMA, then all
//     writing -> each pipe idle 60%+ of the time).
//     Epilogue back to direct stores (v4's LDS-staged full-line epilogue
//     did NOT reduce WRITE_SIZE: the ~57MB extra write traffic is the
//     harness memset drain, not partial-line eviction).
// v3: left pad via in-register ones-select; Bt laid out for 1 KB coalesced
//     wave loads; K-loop fully unrolled; B fragments prefetched.

typedef __bf16 bf16x8 __attribute__((ext_vector_type(8)));
typedef float  f32x4  __attribute__((ext_vector_type(4)));

// ---- BtL[(ks*16 + wv*4 + nt)*64 + q*16 + t16][j] = bf16(exp(off[i][c][p]))
// where inst i = wv*64+nt*16+t16, c = c8*8+j, ks = 2*p + (c8>>2), q = c8&3.
__global__ void mex_prep_b(const float* __restrict__ off, __bf16* __restrict__ Bt) {
    const int i = blockIdx.x * 4 + (threadIdx.x >> 6);  // instance
    const int c = threadIdx.x & 63;                     // channel
    const int c8 = c >> 3, j = c & 7;
    const int wv = i >> 6, nt = (i >> 4) & 3, t16 = i & 15;
    const int q  = c8 & 3;
    const float* oi = off + i * 576;
    #pragma unroll
    for (int p = 0; p < 9; ++p) {
        float v = oi[c * 9 + p];                        // original k = c*9 + p
        const int ks    = p * 2 + (c8 >> 2);
        const int chunk = (ks * 16 + wv * 4 + nt) * 64 + q * 16 + t16;
        Bt[chunk * 8 + j] = (__bf16)__expf(v);
    }
}

// ---- main fused kernel ----------------------------------------------------
__global__ __launch_bounds__(256, 2) void mex_main(
        const float* __restrict__ x,
        const __bf16* __restrict__ Bt,
        float* __restrict__ out) {
    // two buffers: [buf 0..1][hl 0..4][w 0..63][chunk 0..7] bf16x8 = 81920 B
    __shared__ bf16x8 lds8[2 * 2560];

    const int bid = blockIdx.x;      // 0..511
    // XCD-chunked swizzle (512 % 8 == 0 -> bijective)
    const int wid  = ((bid & 7) << 6) | (bid >> 3);
    const int b    = wid >> 3;
    const int j2   = wid & 7;
    const int oh0a = j2 << 2;        // tile0: oh rows oh0a, oh0a+1
    const int oh0b = oh0a + 2;       // tile1: oh rows oh0b, oh0b+1
    const int tid  = threadIdx.x;
    const int wv   = tid >> 6;
    const int lane = tid & 63;

    bf16x8 one8;
    #pragma unroll
    for (int j = 0; j < 8; ++j) one8[j] = (__bf16)1.0f;

    // ---- top pad for tile0 (h_global = -1), only j2 == 0 -----------------
    if (oh0a == 0) {
        #pragma unroll
        for (int i = 0; i < 2; ++i) lds8[tid + i * 256] = one8;
    }

    // staging geometry: thread t -> w-pair wp (w0 = 2*wp), c-chunk c8.
    // swizzled slot c8 ^ (wp&7) == c8 ^ ((w>>1)&7) for both w0, w0+1.
    const int wp  = tid & 31;
    const int w0  = wp << 1;
    const int c8  = tid >> 5;
    const int c8p = c8 ^ (wp & 7);
    const float* xb = x + ((size_t)b << 18) + w0;   // + c*4096 + h*64

    // ---- stage tile0: x -> exp -> bf16 -> swizzled LDS (chained) ---------
    #pragma unroll
    for (int hl = 0; hl < 5; ++hl) {
        const int hg = 2 * oh0a - 1 + hl;           // -1..31
        if (hg >= 0) {                              // block-uniform
            const float* xp = xb + (hg << 6);
            float2 v[8];
            #pragma unroll
            for (int k = 0; k < 8; ++k)
                v[k] = *(const float2*)(xp + (((c8 << 3) + k) << 12));
            bf16x8 ca, cb;
            #pragma unroll
            for (int k = 0; k < 8; ++k) {
                ca[k] = (__bf16)__expf(v[k].x);
                cb[k] = (__bf16)__expf(v[k].y);
            }
            bf16x8* dst = lds8 + hl * 512 + w0 * 8 + c8p;
            dst[0] = ca;        // w = w0
            dst[8] = cb;        // w = w0+1 (same swizzle slot)
        }
    }

    // ---- issue ALL tile1 loads now; they fly under tile0's K-loop --------
    float2 v1[40];
    #pragma unroll
    for (int hl = 0; hl < 5; ++hl) {
        const int hg = 2 * oh0b - 1 + hl;           // 3..63, never padded
        const float* xp = xb + (hg << 6);
        #pragma unroll
        for (int k = 0; k < 8; ++k)
            v1[hl * 8 + k] = *(const float2*)(xp + (((c8 << 3) + k) << 12));
    }

    // ---- first B fragments -----------------------------------------------
    const bf16x8* __restrict__ Btv = (const bf16x8*)Bt;
    const int wv4 = wv << 2;
    bf16x8 bcur[4];
    #pragma unroll
    for (int nt = 0; nt < 4; ++nt)
        bcur[nt] = Btv[(wv4 + nt) * 64 + lane];     // ks = 0

    const int t16 = tid & 15;
    const int q   = (tid >> 4) & 3;
    int hb[4], wo2[4];
    #pragma unroll
    for (int mt = 0; mt < 4; ++mt) {
        const int m = mt * 16 + t16;
        wo2[mt] = (m & 31) << 1;      // 2*ow
        hb[mt]  = (m >> 5) << 7;      // (2*ohl) * 64
    }
    const float lK = 6.356107660695891f;   // log(576)

    // K-loop over one staged buffer
    auto kloop = [&](const bf16x8* __restrict__ L, f32x4 (&acc)[4][4],
                     bf16x8 (&bc)[4]) {
        #pragma unroll
        for (int ks = 0; ks < 18; ++ks) {
            const int p  = ks >> 1;
            const int fh = (p * 11) >> 5;          // p/3 (const after unroll)
            const int fw = p - fh * 3;
            const int ccq = ((ks & 1) << 2) + q;
            bf16x8 a[4];
            #pragma unroll
            for (int mt = 0; mt < 4; ++mt) {
                const int wc  = wo2[mt] + fw - 1;  // w_global, -1..63
                const int pad = wc < 0;            // only fw==0 & ow==0
                const int wcl = pad ? 0 : wc;
                const int row = hb[mt] + fh * 64 + wcl;  // (2*ohl+fh)*64 + w
                bf16x8 vv = L[row * 8 + (ccq ^ ((wcl >> 1) & 7))];
                a[mt] = pad ? one8 : vv;
            }
            bf16x8 bnext[4];
            if (ks < 17) {
                #pragma unroll
                for (int nt = 0; nt < 4; ++nt)
                    bnext[nt] = Btv[((ks + 1) * 16 + wv4 + nt) * 64 + lane];
            }
            #pragma unroll
            for (int mt = 0; mt < 4; ++mt)
                #pragma unroll
                for (int nt = 0; nt < 4; ++nt)
                    acc[mt][nt] = __builtin_amdgcn_mfma_f32_16x16x32_bf16(
                        a[mt], bc[nt], acc[mt][nt], 0, 0, 0);
            #pragma unroll
            for (int nt = 0; nt < 4; ++nt) bc[nt] = bnext[nt];
        }
    };

    // direct-store epilogue: y = log(S) - log(576)
    auto epilogue = [&](f32x4 (&acc)[4][4], int oh0) {
        #pragma unroll
        for (int mt = 0; mt < 4; ++mt) {
            const int m   = mt * 16 + (q << 2);    // C/D: row = q*4 + reg
            const int ohl = m >> 5;
            const int owi = m & 31;
            const int orow = (oh0 + ohl) * 32 + owi;
            #pragma unroll
            for (int nt = 0; nt < 4; ++nt) {
                const int inst = wv * 64 + nt * 16 + t16;  // C/D: col = t16
                f32x4 r;
                #pragma unroll
                for (int j = 0; j < 4; ++j)
                    r[j] = __logf(acc[mt][nt][j]) - lK;
                *(f32x4*)(out + (((size_t)b * 256 + inst) * 1024 + orow)) = r;
            }
        }
    };

    __syncthreads();   // B0: buf0 staged

    f32x4 acc0[4][4];
    #pragma unroll
    for (int mt = 0; mt < 4; ++mt)
        #pragma unroll
        for (int nt = 0; nt < 4; ++nt) acc0[mt][nt] = (f32x4)(0.0f);
    kloop(lds8, acc0, bcur);

    // ---- finish-stage tile1 (loads have landed under the K-loop) ---------
    #pragma unroll
    for (int hl = 0; hl < 5; ++hl) {
        bf16x8 ca, cb;
        #pragma unroll
        for (int k = 0; k < 8; ++k) {
            ca[k] = (__bf16)__expf(v1[hl * 8 + k].x);
            cb[k] = (__bf16)__expf(v1[hl * 8 + k].y);
        }
        bf16x8* dst = lds8 + 2560 + hl * 512 + w0 * 8 + c8p;
        dst[0] = ca;
        dst[8] = cb;
    }
    #pragma unroll
    for (int nt = 0; nt < 4; ++nt)
        bcur[nt] = Btv[(wv4 + nt) * 64 + lane];     // reload ks = 0

    __syncthreads();   // B1: buf1 staged

    // epilogue(t0) sits in the same scheduling region as kloop(t1):
    // logf/global-stores interleave with MFMA/ds_reads.
    epilogue(acc0, oh0a);

    f32x4 acc1[4][4];
    #pragma unroll
    for (int mt = 0; mt < 4; ++mt)
        #pragma unroll
        for (int nt = 0; nt < 4; ++nt) acc1[mt][nt] = (f32x4)(0.0f);
    kloop(lds8 + 2560, acc1, bcur);

    epilogue(acc1, oh0b);
}

extern "C" void kernel_launch(void* const* d_in, const int* in_sizes, int n_in,
                              void* d_out, int out_size, void* d_ws, size_t ws_size,
                              hipStream_t stream) {
    const float* x   = (const float*)d_in[0];   // (64,64,64,64) fp32
    const float* off = (const float*)d_in[1];   // (1,256,64,3,3) fp32
    float* out = (float*)d_out;                 // (64,256,32,32) fp32
    __bf16* Bt = (__bf16*)d_ws;                 // 294912 B

    mex_prep_b<<<64, 256, 0, stream>>>(off, Bt);
    mex_main<<<512, 256, 0, stream>>>(x, Bt, out);
}